// Round 8
// baseline (256.539 us; speedup 1.0000x reference)
//
#include <hip/hip_runtime.h>
#include <math.h>

// CapsuleLayer dynamic routing — round 8.
// B=64, N=4096, I=8, C=32, D=16, 3 routing iterations.
//
// Round-7 post-mortem: 47 us/pass, VALUBusy 57%, stall-bound: per-b serial
// softmax chains (logit->exp->4 DPP->2 swizzle ~170 cyc latency) + top-of-loop
// W-fragment loads, with VGPR squeezed to 64 blocking ILP. Round 8: Ocum in
// registers (not LDS), phase-split per s (A: hat+logit for all 8 b; B: 8
// independent exp/reduce chains interleaved; C: weighted accumulate), and
// launch_bounds(256,3) so the phase arrays (wv 32 + hh 32 + acc 32 + oc 32)
// live in ~160 VGPRs without spilling.
//
// ws: Wh f16 [n][k][l][8i] 32 MiB | xh f16 [n][b][8i] 4 MiB |
//     partial f16 [block 1024][bl 8][l 64][8cj] 8 MiB | OcumG f16 [b][l][8i] 64 KiB

typedef __fp16 h2 __attribute__((ext_vector_type(2)));

#define DPP_ADD(v, ctrl) ((v) + __int_as_float(__builtin_amdgcn_mov_dpp(__float_as_int(v), (ctrl), 0xf, 0xf, true)))
// quad_perm[1,0,3,2]=0xB1 (xor1), quad_perm[2,3,0,1]=0x4E (xor2),
// row_ror:4=0x124, row_ror:8=0x128

__device__ __forceinline__ float fdot2(h2 a, h2 b, float c) {
    return __builtin_amdgcn_fdot2(a, b, c, false);
}

// ---- conversion: blocks 0..4095 -> W, 4096..5119 -> x ----------------------

__global__ __launch_bounds__(256) void convert_all(const float* __restrict__ W,
                                                   const float* __restrict__ x,
                                                   ushort* __restrict__ Wh,
                                                   ushort* __restrict__ xh) {
    const int t = threadIdx.x;
    if (blockIdx.x < 4096) {
        const int n = blockIdx.x;
        const int cj0 = 2 * t;                       // even
        const int c = cj0 >> 4, j0 = cj0 & 15;
        const float* src = W + (size_t)c * 524288 + (size_t)n * 128 + j0 * 8;
        float4 a = *reinterpret_cast<const float4*>(src);
        float4 b = *reinterpret_cast<const float4*>(src + 4);
        float4 cc = *reinterpret_cast<const float4*>(src + 8);
        float4 d = *reinterpret_cast<const float4*>(src + 12);
        __fp16 qa[8] = {(__fp16)a.x, (__fp16)a.y, (__fp16)a.z, (__fp16)a.w,
                        (__fp16)b.x, (__fp16)b.y, (__fp16)b.z, (__fp16)b.w};
        __fp16 qb[8] = {(__fp16)cc.x, (__fp16)cc.y, (__fp16)cc.z, (__fp16)cc.w,
                        (__fp16)d.x, (__fp16)d.y, (__fp16)d.z, (__fp16)d.w};
        uint4* dst = reinterpret_cast<uint4*>(Wh);
        const int l = t >> 2, k0 = cj0 & 7;          // cj0 = l*8 + k0
        dst[((size_t)n * 8 + k0) * 64 + l] = *reinterpret_cast<uint4*>(qa);
        dst[((size_t)n * 8 + k0 + 1) * 64 + l] = *reinterpret_cast<uint4*>(qb);
    } else {
        const int gid = (blockIdx.x - 4096) * 256 + t;    // 0..262143
        const int b = gid >> 12, n = gid & 4095;
        const float* src = x + (size_t)b * 32768 + (size_t)n * 8;
        float4 a = *reinterpret_cast<const float4*>(src);
        float4 c = *reinterpret_cast<const float4*>(src + 4);
        __fp16 q[8] = {(__fp16)a.x, (__fp16)a.y, (__fp16)a.z, (__fp16)a.w,
                       (__fp16)c.x, (__fp16)c.y, (__fp16)c.z, (__fp16)c.w};
        reinterpret_cast<uint4*>(xh)[(size_t)n * 64 + b] = *reinterpret_cast<uint4*>(q);
    }
}

// ---- main fused routing pass ----------------------------------------------

template <int UNI>
__global__ __launch_bounds__(256, 3) void fused_pass(const ushort* __restrict__ Wh,
                                                     const ushort* __restrict__ xh,
                                                     const ushort* __restrict__ OcumG,
                                                     uint4* __restrict__ partialU) {
    const int ntile = blockIdx.x & 127;              // XCD = blockIdx%8 = ntile%8
    const int bg = blockIdx.x >> 7;                  // 0..7
    const int n0 = ntile * 32, b0 = bg * 8;
    const int t = threadIdx.x, lane = t & 63, w = t >> 6;

    __shared__ __align__(16) uint4 smem[2048];       // 32 KB (xls in front; epilogue reuses)
    uint4* xls = smem;                               // 256: [nl 32][bl 8]

    const uint4* xhu = reinterpret_cast<const uint4*>(xh);
    {
        int nl = t >> 3, bl = t & 7;
        xls[t] = xhu[(size_t)(n0 + nl) * 64 + b0 + bl];
    }

    // Ocum fragments in REGISTERS (not LDS): per lane, one uint4 per b
    uint4 oc[8];
    if (!UNI) {
        const uint4* ocg = reinterpret_cast<const uint4*>(OcumG);
        #pragma unroll
        for (int b = 0; b < 8; ++b)
            oc[b] = ocg[(size_t)(b0 + b) * 64 + lane];
    }
    __syncthreads();

    h2 acc[8][4];
    #pragma unroll
    for (int b = 0; b < 8; ++b)
        #pragma unroll
        for (int jp = 0; jp < 4; ++jp) acc[b][jp] = (h2)(__fp16)0.f;

    const uint4* Whu = reinterpret_cast<const uint4*>(Wh);
    const int nA = n0 + w * 8;                       // wave owns 8 n
    const uint4* wp = Whu + (size_t)nA * 512 + lane; // per-s step: +512 uint4

    #pragma unroll 1
    for (int s = 0; s < 8; ++s) {
        uint4 wv[8];                                 // single buffer, const-indexed
        #pragma unroll
        for (int k = 0; k < 8; ++k) wv[k] = wp[k * 64];
        wp += 512;
        const h2* wh = reinterpret_cast<const h2*>(wv);
        const uint4* xrow = xls + (w * 8 + s) * 8;

        // ---- phase A: hat + pair-logit for all 8 b ----
        h2 hh[8][4];
        float p[8];
        #pragma unroll
        for (int b = 0; b < 8; ++b) {
            uint4 xv = xrow[b];                      // wave-uniform: LDS broadcast
            const h2* xp = reinterpret_cast<const h2*>(&xv);
            float h[8];
            #pragma unroll
            for (int k = 0; k < 8; ++k) {
                float sacc = fdot2(wh[k * 4 + 0], xp[0], 0.f);
                sacc = fdot2(wh[k * 4 + 1], xp[1], sacc);
                sacc = fdot2(wh[k * 4 + 2], xp[2], sacc);
                h[k] = fdot2(wh[k * 4 + 3], xp[3], sacc);
            }
            #pragma unroll
            for (int jp = 0; jp < 4; ++jp)
                hh[b][jp] = __builtin_amdgcn_cvt_pkrtz(h[2 * jp], h[2 * jp + 1]);
            if (!UNI) {
                const h2* op = reinterpret_cast<const h2*>(&oc[b]);
                float pp = fdot2(op[0], hh[b][0], 0.f);
                pp = fdot2(op[1], hh[b][1], pp);
                pp = fdot2(op[2], hh[b][2], pp);
                pp = fdot2(op[3], hh[b][3], pp);
                p[b] = DPP_ADD(pp, 0xB1);            // pair-sum -> full logit per c
            }
        }

        // ---- phase B: 8 independent softmax chains (interleaved by scheduler)
        h2 cs[8];
        if (UNI) {
            #pragma unroll
            for (int b = 0; b < 8; ++b) {
                cs[b].x = (__fp16)0.03125f;
                cs[b].y = cs[b].x;
            }
        } else {
            float e[8], sm[8];
            #pragma unroll
            for (int b = 0; b < 8; ++b) e[b] = __expf(p[b]);   // |p| small: no max-sub
            #pragma unroll
            for (int b = 0; b < 8; ++b) {
                // 64-lane sum = 2 * denominator (each c duplicated in a pair)
                float v = DPP_ADD(e[b], 0xB1);
                v = DPP_ADD(v, 0x4E);                // quad sum
                v = DPP_ADD(v, 0x124);               // + row_ror:4
                v = DPP_ADD(v, 0x128);               // + row_ror:8 -> row(16) sum
                v += __shfl_xor(v, 16, 64);
                v += __shfl_xor(v, 32, 64);          // full 64-lane sum
                sm[b] = v;
            }
            #pragma unroll
            for (int b = 0; b < 8; ++b) {
                float ccf = (e[b] + e[b]) * __builtin_amdgcn_rcpf(sm[b]);
                cs[b].x = (__fp16)ccf;
                cs[b].y = cs[b].x;
            }
        }

        // ---- phase C: weighted accumulate ----
        #pragma unroll
        for (int b = 0; b < 8; ++b)
            #pragma unroll
            for (int jp = 0; jp < 4; ++jp) acc[b][jp] = hh[b][jp] * cs[b] + acc[b][jp];
    }

    // ---- epilogue: cross-wave (same b-set, different n) reduce in LDS ----
    __syncthreads();
    #pragma unroll
    for (int b = 0; b < 8; ++b)
        smem[w * 512 + b * 64 + lane] = *reinterpret_cast<uint4*>(&acc[b][0]);
    __syncthreads();
    for (int o = t; o < 512; o += 256) {             // o = bl*64 + l
        float sv[8] = {0.f, 0.f, 0.f, 0.f, 0.f, 0.f, 0.f, 0.f};
        #pragma unroll
        for (int ww = 0; ww < 4; ++ww) {
            uint4 v = smem[ww * 512 + o];
            const h2* vh = reinterpret_cast<const h2*>(&v);
            #pragma unroll
            for (int q = 0; q < 4; ++q) {
                sv[2 * q] += (float)vh[q].x;
                sv[2 * q + 1] += (float)vh[q].y;
            }
        }
        h2 pk[4];
        #pragma unroll
        for (int q = 0; q < 4; ++q)
            pk[q] = __builtin_amdgcn_cvt_pkrtz(sv[2 * q], sv[2 * q + 1]);
        partialU[(size_t)blockIdx.x * 512 + o] = *reinterpret_cast<uint4*>(pk);
    }
}

// ---- final reduce + squash + Ocum update ----------------------------------

__global__ __launch_bounds__(256) void reduce_squash(const unsigned* __restrict__ partial32,
                                                     ushort* __restrict__ OcumG,
                                                     float* __restrict__ out,
                                                     int passIdx) {
    const int tid = blockIdx.x * 256 + threadIdx.x;  // 0..16383
    const int b = tid >> 8, cjp = tid & 255;         // cj = 2*cjp
    const int bg = b >> 3, bl = b & 7;
    const unsigned base = ((unsigned)bg * 128 * 512 + (unsigned)bl * 64) * 4 + cjp;
    float sx = 0.f, sy = 0.f;
    for (int nt = 0; nt < 128; ++nt) {
        union { unsigned u; h2 h; } v;
        v.u = partial32[base + nt * 2048];
        sx += (float)v.h.x;
        sy += (float)v.h.y;
    }
    float s2 = sx * sx + sy * sy;                    // 16 j live in 8 lanes
    s2 += __shfl_xor(s2, 1, 64);
    s2 += __shfl_xor(s2, 2, 64);
    s2 += __shfl_xor(s2, 4, 64);
    float scale = (s2 / (1.f + s2)) / sqrtf(s2 + 1e-7f);
    float o0 = scale * sx, o1 = scale * sy;

    unsigned* ocp = reinterpret_cast<unsigned*>(OcumG) + b * 256 + cjp;
    float a0 = o0, a1 = o1;
    if (passIdx) {
        union { unsigned u; h2 h; } old;
        old.u = *ocp;
        a0 += (float)old.h.x;
        a1 += (float)old.h.y;
    }
    union { h2 h; unsigned u; } nw;
    nw.h = __builtin_amdgcn_cvt_pkrtz(a0, a1);
    *ocp = nw.u;

    if (passIdx == 2) {
        out[b * 512 + cjp * 2] = o0;
        out[b * 512 + cjp * 2 + 1] = o1;
    }
}

// ---- host ------------------------------------------------------------------

extern "C" void kernel_launch(void* const* d_in, const int* in_sizes, int n_in,
                              void* d_out, int out_size, void* d_ws, size_t ws_size,
                              hipStream_t stream) {
    const float* x = (const float*)d_in[0];
    const float* W = (const float*)d_in[1];
    float* out = (float*)d_out;

    char* ws = (char*)d_ws;
    ushort* Wh = (ushort*)ws;                                   // 32 MiB
    ushort* xh = (ushort*)(ws + (size_t)32 * 1024 * 1024);      // 4 MiB
    uint4* partialU = (uint4*)(ws + (size_t)36 * 1024 * 1024);  // 8 MiB
    ushort* OcumG = (ushort*)(ws + (size_t)44 * 1024 * 1024);   // 64 KiB

    convert_all<<<5120, 256, 0, stream>>>(W, x, Wh, xh);

    for (int pass = 0; pass < 3; ++pass) {
        if (pass == 0)
            fused_pass<1><<<1024, 256, 0, stream>>>(Wh, xh, OcumG, partialU);
        else
            fused_pass<0><<<1024, 256, 0, stream>>>(Wh, xh, OcumG, partialU);
        reduce_squash<<<64, 256, 0, stream>>>((const unsigned*)partialU, OcumG, out, pass);
    }
}